// Round 1
// baseline (729.865 us; speedup 1.0000x reference)
//
#include <hip/hip_runtime.h>
#include <hip/hip_bf16.h>
#include <math.h>

#define NTOK 49
#define NH 12
#define HD 32
#define CDIM 384
#define NWIN 64
#define BWIN 2048

typedef __bf16 bf16x8 __attribute__((ext_vector_type(8)));
typedef float f32x4 __attribute__((ext_vector_type(4)));

// ---------------- CPB MLP: bias_tab[169][12] ----------------
__global__ void cpb_mlp_kernel(const float* __restrict__ w1, const float* __restrict__ b1,
                               const float* __restrict__ w2, float* __restrict__ bias_tab) {
    int t = blockIdx.x * blockDim.x + threadIdx.x;
    if (t >= 169 * NH) return;
    int r = t / NH, h = t - (t / NH) * NH;
    int i = r / 13, j = r - (r / 13) * 13;
    float a0 = (float)(i - 6) * (8.0f / 6.0f);
    float a1 = (float)(j - 6) * (8.0f / 6.0f);
    float c0 = copysignf(log2f(fabsf(a0) + 1.0f) * (1.0f / 3.0f), a0);
    float c1 = copysignf(log2f(fabsf(a1) + 1.0f) * (1.0f / 3.0f), a1);
    float sum = 0.f;
    for (int k = 0; k < 512; ++k) {
        float hid = c0 * w1[2 * k] + c1 * w1[2 * k + 1] + b1[k];
        hid = fmaxf(hid, 0.f);
        sum += hid * w2[h * 512 + k];
    }
    bias_tab[r * NH + h] = sum;
}

// ---------------- rpb[12][49][49] = 16*sigmoid(bias_tab[rpi]) ----------------
__global__ void rpb_kernel(const float* __restrict__ bias_tab, float* __restrict__ rpb) {
    int idx = blockIdx.x * blockDim.x + threadIdx.x;
    if (idx >= NH * NTOK * NTOK) return;
    int h = idx / (NTOK * NTOK);
    int rem = idx - h * (NTOK * NTOK);
    int i = rem / NTOK, j = rem - (rem / NTOK) * NTOK;
    int chi = i / 7, cwi = i - chi * 7;
    int chj = j / 7, cwj = j - chj * 7;
    int rpi = (chi - chj + 6) * 13 + (cwi - cwj + 6);
    float x = bias_tab[rpi * NH + h];
    rpb[idx] = 16.f / (1.f + __expf(-x));
}

// ---------------- MFMA GEMM: C = A @ Bt^T (+bias) ----------------
// MODE 0: A = x (f32 [100352][384]), Bt = qkv_w [1152][384]; out -> q/k/v bf16 [b][h][n][d] (+q/v bias)
// MODE 1: A = attn_out (bf16 [100352][384]), Bt = proj_w [384][384]; out -> f32 d_out (+proj bias)
template <int MODE>
__global__ __launch_bounds__(256) void gemm_mfma(
    const void* __restrict__ Av, const float* __restrict__ Bt,
    const float* __restrict__ qbias, const float* __restrict__ vbias,
    __bf16* __restrict__ qkvout, float* __restrict__ fout,
    const float* __restrict__ fbias)
{
    __shared__ __bf16 As[128 * 40];  // padded: 40 bf16 (80B) per 32-k row
    __shared__ __bf16 Bs[128 * 40];
    const int tid = threadIdx.x;
    const int gx = blockIdx.x, gy = blockIdx.y;
    const int lane = tid & 63;
    const int wid = tid >> 6;
    const int wr = (wid >> 1) * 64;
    const int wc = (wid & 1) * 64;
    const int fr = lane & 15;   // fragment row/col select
    const int fq = lane >> 4;   // k-group (8 consecutive k)
    const int srow = tid >> 1;  // staging row 0..127
    const int skh = tid & 1;    // staging k-half (16 elems)

    f32x4 acc[4][4];
#pragma unroll
    for (int m = 0; m < 4; ++m)
#pragma unroll
        for (int n = 0; n < 4; ++n)
            acc[m][n] = (f32x4){0.f, 0.f, 0.f, 0.f};

    const size_t arow = (size_t)(gx * 128 + srow) * CDIM;
    const size_t brow = (size_t)(gy * 128 + srow) * CDIM;

    for (int k0 = 0; k0 < CDIM; k0 += 32) {
        const int gk = k0 + skh * 16;
        bf16x8 a0, a1, b0, b1;
        if (MODE == 0) {
            const float* p = (const float*)Av + arow + gk;
            f32x4 v0 = *(const f32x4*)(p);
            f32x4 v1 = *(const f32x4*)(p + 4);
            f32x4 v2 = *(const f32x4*)(p + 8);
            f32x4 v3 = *(const f32x4*)(p + 12);
#pragma unroll
            for (int e = 0; e < 4; ++e) {
                a0[e] = (__bf16)v0[e]; a0[e + 4] = (__bf16)v1[e];
                a1[e] = (__bf16)v2[e]; a1[e + 4] = (__bf16)v3[e];
            }
        } else {
            const __bf16* p = (const __bf16*)Av + arow + gk;
            a0 = *(const bf16x8*)(p);
            a1 = *(const bf16x8*)(p + 8);
        }
        {
            const float* p = Bt + brow + gk;
            f32x4 v0 = *(const f32x4*)(p);
            f32x4 v1 = *(const f32x4*)(p + 4);
            f32x4 v2 = *(const f32x4*)(p + 8);
            f32x4 v3 = *(const f32x4*)(p + 12);
#pragma unroll
            for (int e = 0; e < 4; ++e) {
                b0[e] = (__bf16)v0[e]; b0[e + 4] = (__bf16)v1[e];
                b1[e] = (__bf16)v2[e]; b1[e + 4] = (__bf16)v3[e];
            }
        }
        *(bf16x8*)&As[srow * 40 + skh * 16] = a0;
        *(bf16x8*)&As[srow * 40 + skh * 16 + 8] = a1;
        *(bf16x8*)&Bs[srow * 40 + skh * 16] = b0;
        *(bf16x8*)&Bs[srow * 40 + skh * 16 + 8] = b1;
        __syncthreads();

        bf16x8 af[4], bfr[4];
#pragma unroll
        for (int m = 0; m < 4; ++m)
            af[m] = *(const bf16x8*)&As[(wr + m * 16 + fr) * 40 + fq * 8];
#pragma unroll
        for (int n = 0; n < 4; ++n)
            bfr[n] = *(const bf16x8*)&Bs[(wc + n * 16 + fr) * 40 + fq * 8];
#pragma unroll
        for (int m = 0; m < 4; ++m)
#pragma unroll
            for (int n = 0; n < 4; ++n)
                acc[m][n] = __builtin_amdgcn_mfma_f32_16x16x32_bf16(af[m], bfr[n], acc[m][n], 0, 0, 0);
        __syncthreads();
    }

    if (MODE == 0) {
        const int colbase = gy * 128;
        const int part = colbase / CDIM;           // uniform per block (384 = 3*128)
        const int pcolbase = colbase - part * CDIM;
        __bf16* dst = qkvout + (size_t)part * ((size_t)BWIN * NH * NTOK * HD);
#pragma unroll
        for (int m = 0; m < 4; ++m) {
#pragma unroll
            for (int r = 0; r < 4; ++r) {
                const int row = gx * 128 + wr + m * 16 + fq * 4 + r;
                const int b = row / NTOK;
                const int nn = row - b * NTOK;
#pragma unroll
                for (int n = 0; n < 4; ++n) {
                    const int pcol = pcolbase + wc + n * 16 + fr;
                    float val = acc[m][n][r];
                    if (part == 0) val += qbias[pcol];
                    if (part == 2) val += vbias[pcol];
                    const int h = pcol >> 5, d = pcol & 31;
                    dst[(((size_t)b * NH + h) * NTOK + nn) * HD + d] = (__bf16)val;
                }
            }
        }
    } else {
#pragma unroll
        for (int m = 0; m < 4; ++m) {
#pragma unroll
            for (int r = 0; r < 4; ++r) {
                const int row = gx * 128 + wr + m * 16 + fq * 4 + r;
                float* orow = fout + (size_t)row * CDIM + gy * 128 + wc;
#pragma unroll
                for (int n = 0; n < 4; ++n) {
                    const int col = gy * 128 + wc + n * 16 + fr;
                    orow[n * 16 + fr] = acc[m][n][r] + fbias[col];
                }
            }
        }
    }
}

// ---------------- attention: one (b,h) per 64-thread block ----------------
__global__ __launch_bounds__(64) void attn_kernel(
    const __bf16* __restrict__ qb, const __bf16* __restrict__ kb,
    const __bf16* __restrict__ vb, const float* __restrict__ mask,
    const float* __restrict__ rpb, const float* __restrict__ lscale,
    __bf16* __restrict__ aout)
{
    const int bh = blockIdx.x;
    const int b = bh / NH;
    const int h = bh - b * NH;
    const int w = b & (NWIN - 1);
    const int tid = threadIdx.x;

    __shared__ float ks[NTOK][HD];
    __shared__ float vs[NTOK][HD];
    __shared__ float invk[NTOK];

    const __bf16* kg = kb + (size_t)bh * (NTOK * HD);
    const __bf16* vg = vb + (size_t)bh * (NTOK * HD);
    for (int c = tid; c < 2 * NTOK * HD / 8; c += 64) {
        const int mat = (c >= NTOK * HD / 8);
        const int cc = mat ? c - NTOK * HD / 8 : c;
        bf16x8 raw = *(const bf16x8*)((mat ? vg : kg) + cc * 8);
        float* dstf = (mat ? &vs[0][0] : &ks[0][0]) + cc * 8;
#pragma unroll
        for (int e = 0; e < 8; ++e) dstf[e] = (float)raw[e];
    }
    __syncthreads();
    if (tid < NTOK) {
        float s = 0.f;
#pragma unroll
        for (int d = 0; d < HD; ++d) s += ks[tid][d] * ks[tid][d];
        invk[tid] = 1.0f / fmaxf(sqrtf(s), 1e-12f);
    }
    __syncthreads();
    if (tid < NTOK) {
        float q[HD];
        const __bf16* qg = qb + (size_t)bh * (NTOK * HD) + tid * HD;
#pragma unroll
        for (int c = 0; c < HD / 8; ++c) {
            bf16x8 raw = *(const bf16x8*)(qg + c * 8);
#pragma unroll
            for (int e = 0; e < 8; ++e) q[c * 8 + e] = (float)raw[e];
        }
        float s = 0.f;
#pragma unroll
        for (int d = 0; d < HD; ++d) s += q[d] * q[d];
        const float scale = __expf(fminf(lscale[h], 4.6051702f));
        const float pre = scale / fmaxf(sqrtf(s), 1e-12f);
#pragma unroll
        for (int d = 0; d < HD; ++d) q[d] *= pre;

        float p[NTOK];
        const float* rpbrow = rpb + ((size_t)h * NTOK + tid) * NTOK;
        const float* mrow = mask + ((size_t)w * NTOK + tid) * NTOK;
#pragma unroll
        for (int j = 0; j < NTOK; ++j) {
            float dot = 0.f;
#pragma unroll
            for (int d = 0; d < HD; ++d) dot += q[d] * ks[j][d];
            p[j] = dot * invk[j] + rpbrow[j] + mrow[j];
        }
        float mx = -1e30f;
#pragma unroll
        for (int j = 0; j < NTOK; ++j) mx = fmaxf(mx, p[j]);
        float sum = 0.f;
#pragma unroll
        for (int j = 0; j < NTOK; ++j) { p[j] = __expf(p[j] - mx); sum += p[j]; }
        const float rs = 1.f / sum;

        float o[HD];
#pragma unroll
        for (int d = 0; d < HD; ++d) o[d] = 0.f;
#pragma unroll
        for (int j = 0; j < NTOK; ++j) {
            const float pj = p[j];
#pragma unroll
            for (int d = 0; d < HD; ++d) o[d] += pj * vs[j][d];
        }
        __bf16* dst = aout + ((size_t)(b * NTOK + tid)) * CDIM + h * HD;
#pragma unroll
        for (int c = 0; c < HD / 8; ++c) {
            bf16x8 ov;
#pragma unroll
            for (int e = 0; e < 8; ++e) ov[e] = (__bf16)(o[c * 8 + e] * rs);
            *(bf16x8*)(dst + c * 8) = ov;
        }
    }
}

extern "C" void kernel_launch(void* const* d_in, const int* in_sizes, int n_in,
                              void* d_out, int out_size, void* d_ws, size_t ws_size,
                              hipStream_t stream) {
    const float* x      = (const float*)d_in[0];
    const float* mask   = (const float*)d_in[1];
    const float* qkv_w  = (const float*)d_in[2];
    const float* q_bias = (const float*)d_in[3];
    const float* v_bias = (const float*)d_in[4];
    const float* lscale = (const float*)d_in[5];
    const float* cpb_w1 = (const float*)d_in[6];
    const float* cpb_b1 = (const float*)d_in[7];
    const float* cpb_w2 = (const float*)d_in[8];
    const float* proj_w = (const float*)d_in[9];
    const float* proj_b = (const float*)d_in[10];
    float* out = (float*)d_out;

    const size_t QKVELEMS = (size_t)BWIN * NH * NTOK * HD;  // 38,535,168
    __bf16* qkvbuf = (__bf16*)d_ws;                 // q,k,v: 3*QKVELEMS bf16
    __bf16* aoutbuf = qkvbuf + 3 * QKVELEMS;        // attn out: QKVELEMS bf16
    float* bias_tab = (float*)(aoutbuf + QKVELEMS); // 169*12 f32
    float* rpbbuf = bias_tab + 169 * NH;            // 12*49*49 f32

    hipLaunchKernelGGL(cpb_mlp_kernel, dim3(8), dim3(256), 0, stream,
                       cpb_w1, cpb_b1, cpb_w2, bias_tab);
    hipLaunchKernelGGL(rpb_kernel, dim3((NH * NTOK * NTOK + 255) / 256), dim3(256), 0, stream,
                       bias_tab, rpbbuf);
    hipLaunchKernelGGL((gemm_mfma<0>), dim3(784, 9), dim3(256), 0, stream,
                       (const void*)x, qkv_w, q_bias, v_bias, qkvbuf, (float*)nullptr,
                       (const float*)nullptr);
    hipLaunchKernelGGL(attn_kernel, dim3(BWIN * NH), dim3(64), 0, stream,
                       qkvbuf, qkvbuf + QKVELEMS, qkvbuf + 2 * QKVELEMS, mask, rpbbuf, lscale,
                       aoutbuf);
    hipLaunchKernelGGL((gemm_mfma<1>), dim3(784, 3), dim3(256), 0, stream,
                       (const void*)aoutbuf, proj_w, (const float*)nullptr, (const float*)nullptr,
                       (__bf16*)nullptr, out, proj_b);
}

// Round 2
// 676.056 us; speedup vs baseline: 1.0796x; 1.0796x over previous
//
#include <hip/hip_runtime.h>
#include <hip/hip_bf16.h>
#include <math.h>

#define NTOK 49
#define NH 12
#define HD 32
#define CDIM 384
#define NWIN 64
#define BWIN 2048

typedef __bf16 bf16x8 __attribute__((ext_vector_type(8)));
typedef float f32x4 __attribute__((ext_vector_type(4)));

__device__ __forceinline__ void gload_lds16(const void* g, void* l) {
    __builtin_amdgcn_global_load_lds((const __attribute__((address_space(1))) void*)g,
                                     (__attribute__((address_space(3))) void*)l, 16, 0, 0);
}

// ---------------- fp32 -> bf16 weight convert ----------------
__global__ void cvt_f32_bf16(const float* __restrict__ src, __bf16* __restrict__ dst, int n8) {
    int i = blockIdx.x * blockDim.x + threadIdx.x;
    if (i >= n8) return;
    f32x4 a = *(const f32x4*)(src + (size_t)i * 8);
    f32x4 b = *(const f32x4*)(src + (size_t)i * 8 + 4);
    bf16x8 o;
#pragma unroll
    for (int e = 0; e < 4; ++e) { o[e] = (__bf16)a[e]; o[e + 4] = (__bf16)b[e]; }
    *(bf16x8*)(dst + (size_t)i * 8) = o;
}

// ---------------- CPB MLP: bias_tab[169][12] ----------------
__global__ void cpb_mlp_kernel(const float* __restrict__ w1, const float* __restrict__ b1,
                               const float* __restrict__ w2, float* __restrict__ bias_tab) {
    int t = blockIdx.x * blockDim.x + threadIdx.x;
    if (t >= 169 * NH) return;
    int r = t / NH, h = t - (t / NH) * NH;
    int i = r / 13, j = r - (r / 13) * 13;
    float a0 = (float)(i - 6) * (8.0f / 6.0f);
    float a1 = (float)(j - 6) * (8.0f / 6.0f);
    float c0 = copysignf(log2f(fabsf(a0) + 1.0f) * (1.0f / 3.0f), a0);
    float c1 = copysignf(log2f(fabsf(a1) + 1.0f) * (1.0f / 3.0f), a1);
    float sum = 0.f;
    for (int k = 0; k < 512; ++k) {
        float hid = c0 * w1[2 * k] + c1 * w1[2 * k + 1] + b1[k];
        hid = fmaxf(hid, 0.f);
        sum += hid * w2[h * 512 + k];
    }
    bias_tab[r * NH + h] = sum;
}

// ---------------- rpb[12][49][49] = 16*sigmoid(bias_tab[rpi]) ----------------
__global__ void rpb_kernel(const float* __restrict__ bias_tab, float* __restrict__ rpb) {
    int idx = blockIdx.x * blockDim.x + threadIdx.x;
    if (idx >= NH * NTOK * NTOK) return;
    int h = idx / (NTOK * NTOK);
    int rem = idx - h * (NTOK * NTOK);
    int i = rem / NTOK, j = rem - (rem / NTOK) * NTOK;
    int chi = i / 7, cwi = i - chi * 7;
    int chj = j / 7, cwj = j - chj * 7;
    int rpi = (chi - chj + 6) * 13 + (cwi - cwj + 6);
    float x = bias_tab[rpi * NH + h];
    rpb[idx] = 16.f / (1.f + __expf(-x));
}

// ---------------- MFMA GEMM v2: C = A @ Bt^T (+bias) ----------------
// MODE 0: A = x (f32), Bt = qkv_w bf16 [1152][384]; out -> q/k/v bf16 [b][h][n][d] (+q/v bias)
// MODE 1: A = attn_out (bf16), Bt = proj_w bf16 [384][384]; out -> f32 d_out (+proj bias)
// LDS: linear [128][32] bf16, 16B slots XOR-swizzled: phys_slot = log_slot ^ ((row>>1)&3).
// B (and MODE1 A) staged via global_load_lds w=16 with SOURCE-pre-swizzled addresses
// (linear LDS dest, rule #21). MODE0 A reg-staged (fp32 load + cvt) with swizzled ds_write.
template <int MODE, int NBY>
__global__ __launch_bounds__(256) void gemm2(
    const float* __restrict__ Af, const __bf16* __restrict__ Ab,
    const __bf16* __restrict__ Bw,
    const float* __restrict__ qbias, const float* __restrict__ vbias,
    __bf16* __restrict__ qkvout,
    float* __restrict__ fout, const float* __restrict__ fbias)
{
    __shared__ __bf16 As[128 * 32];
    __shared__ __bf16 Bs[128 * 32];
    const int tid = threadIdx.x;
    // XCD-chunked bijective swizzle (grid % 8 == 0), gy-fastest for A-panel reuse
    const int chunk = (784 * NBY) >> 3;
    const int wg = (blockIdx.x & 7) * chunk + (blockIdx.x >> 3);
    const int gx = wg / NBY, gy = wg - (wg / NBY) * NBY;
    const int lane = tid & 63;
    const int wid = tid >> 6;
    const int wr = (wid >> 1) * 64;
    const int wc = (wid & 1) * 64;
    const int fr = lane & 15;
    const int fq = lane >> 4;

    f32x4 acc[4][4];
#pragma unroll
    for (int m = 0; m < 4; ++m)
#pragma unroll
        for (int n = 0; n < 4; ++n)
            acc[m][n] = (f32x4){0.f, 0.f, 0.f, 0.f};

    // MODE0 A reg-staging geometry: 2 threads per row, 16 floats each
    const int arow = tid >> 1;
    const int ahalf = tid & 1;
    const float* aptr = (MODE == 0) ? Af + (size_t)(gx * 128 + arow) * CDIM + ahalf * 16 : nullptr;
    const int axr = (arow >> 1) & 3;
    __bf16* awr0 = &As[arow * 32 + ((ahalf * 2) ^ axr) * 8];
    __bf16* awr1 = &As[arow * 32 + ((ahalf * 2 + 1) ^ axr) * 8];

    for (int k0 = 0; k0 < CDIM; k0 += 32) {
        if (MODE == 0) {
            f32x4 v0 = *(const f32x4*)(aptr + k0);
            f32x4 v1 = *(const f32x4*)(aptr + k0 + 4);
            f32x4 v2 = *(const f32x4*)(aptr + k0 + 8);
            f32x4 v3 = *(const f32x4*)(aptr + k0 + 12);
            bf16x8 c0, c1;
#pragma unroll
            for (int e = 0; e < 4; ++e) {
                c0[e] = (__bf16)v0[e]; c0[e + 4] = (__bf16)v1[e];
                c1[e] = (__bf16)v2[e]; c1[e + 4] = (__bf16)v3[e];
            }
            *(bf16x8*)awr0 = c0;
            *(bf16x8*)awr1 = c1;
        } else {
#pragma unroll
            for (int r = 0; r < 2; ++r) {
                const int s = r * 256 + tid;
                const int row = s >> 2, cp = s & 3;
                const int cl = cp ^ ((row >> 1) & 3);
                gload_lds16(Ab + (size_t)(gx * 128 + row) * CDIM + k0 + cl * 8, &As[s * 8]);
            }
        }
#pragma unroll
        for (int r = 0; r < 2; ++r) {
            const int s = r * 256 + tid;
            const int row = s >> 2, cp = s & 3;
            const int cl = cp ^ ((row >> 1) & 3);
            gload_lds16(Bw + (size_t)(gy * 128 + row) * CDIM + k0 + cl * 8, &Bs[s * 8]);
        }
        __syncthreads();

        bf16x8 af[4], bfr[4];
#pragma unroll
        for (int m = 0; m < 4; ++m) {
            const int row = wr + m * 16 + fr;
            af[m] = *(const bf16x8*)&As[row * 32 + (fq ^ ((row >> 1) & 3)) * 8];
        }
#pragma unroll
        for (int n = 0; n < 4; ++n) {
            const int row = wc + n * 16 + fr;
            bfr[n] = *(const bf16x8*)&Bs[row * 32 + (fq ^ ((row >> 1) & 3)) * 8];
        }
#pragma unroll
        for (int m = 0; m < 4; ++m)
#pragma unroll
            for (int n = 0; n < 4; ++n)
                acc[m][n] = __builtin_amdgcn_mfma_f32_16x16x32_bf16(af[m], bfr[n], acc[m][n], 0, 0, 0);
        __syncthreads();
    }

    if (MODE == 0) {
        const int colbase = gy * 128;
        const int part = colbase / CDIM;
        const int pcolbase = colbase - part * CDIM;
        __bf16* dst = qkvout + (size_t)part * ((size_t)BWIN * NH * NTOK * HD);
#pragma unroll
        for (int m = 0; m < 4; ++m) {
#pragma unroll
            for (int r = 0; r < 4; ++r) {
                const int row = gx * 128 + wr + m * 16 + fq * 4 + r;
                const int b = row / NTOK;
                const int nn = row - b * NTOK;
#pragma unroll
                for (int n = 0; n < 4; ++n) {
                    const int pcol = pcolbase + wc + n * 16 + fr;
                    float val = acc[m][n][r];
                    if (part == 0) val += qbias[pcol];
                    if (part == 2) val += vbias[pcol];
                    const int h = pcol >> 5, d = pcol & 31;
                    dst[(((size_t)b * NH + h) * NTOK + nn) * HD + d] = (__bf16)val;
                }
            }
        }
    } else {
#pragma unroll
        for (int m = 0; m < 4; ++m) {
#pragma unroll
            for (int r = 0; r < 4; ++r) {
                const int row = gx * 128 + wr + m * 16 + fq * 4 + r;
                float* orow = fout + (size_t)row * CDIM + gy * 128 + wc;
#pragma unroll
                for (int n = 0; n < 4; ++n) {
                    const int col = gy * 128 + wc + n * 16 + fr;
                    orow[n * 16 + fr] = acc[m][n][r] + fbias[col];
                }
            }
        }
    }
}

// ---------------- attention: one (b,h) per 64-thread block ----------------
__global__ __launch_bounds__(64) void attn_kernel(
    const __bf16* __restrict__ qb, const __bf16* __restrict__ kb,
    const __bf16* __restrict__ vb, const float* __restrict__ mask,
    const float* __restrict__ rpb, const float* __restrict__ lscale,
    __bf16* __restrict__ aout)
{
    const int bh = blockIdx.x;
    const int b = bh / NH;
    const int h = bh - b * NH;
    const int w = b & (NWIN - 1);
    const int tid = threadIdx.x;

    __shared__ float ks[NTOK][HD];
    __shared__ float vs[NTOK][HD];
    __shared__ float invk[NTOK];

    const __bf16* kg = kb + (size_t)bh * (NTOK * HD);
    const __bf16* vg = vb + (size_t)bh * (NTOK * HD);
    for (int c = tid; c < 2 * NTOK * HD / 8; c += 64) {
        const int mat = (c >= NTOK * HD / 8);
        const int cc = mat ? c - NTOK * HD / 8 : c;
        bf16x8 raw = *(const bf16x8*)((mat ? vg : kg) + cc * 8);
        float* dstf = (mat ? &vs[0][0] : &ks[0][0]) + cc * 8;
#pragma unroll
        for (int e = 0; e < 8; ++e) dstf[e] = (float)raw[e];
    }
    __syncthreads();
    if (tid < NTOK) {
        float s = 0.f;
#pragma unroll
        for (int d = 0; d < HD; ++d) s += ks[tid][d] * ks[tid][d];
        invk[tid] = 1.0f / fmaxf(sqrtf(s), 1e-12f);
    }
    __syncthreads();
    if (tid < NTOK) {
        float q[HD];
        const __bf16* qg = qb + (size_t)bh * (NTOK * HD) + tid * HD;
#pragma unroll
        for (int c = 0; c < HD / 8; ++c) {
            bf16x8 raw = *(const bf16x8*)(qg + c * 8);
#pragma unroll
            for (int e = 0; e < 8; ++e) q[c * 8 + e] = (float)raw[e];
        }
        float s = 0.f;
#pragma unroll
        for (int d = 0; d < HD; ++d) s += q[d] * q[d];
        const float scale = __expf(fminf(lscale[h], 4.6051702f));
        const float pre = scale / fmaxf(sqrtf(s), 1e-12f);
#pragma unroll
        for (int d = 0; d < HD; ++d) q[d] *= pre;

        float p[NTOK];
        const float* rpbrow = rpb + ((size_t)h * NTOK + tid) * NTOK;
        const float* mrow = mask + ((size_t)w * NTOK + tid) * NTOK;
#pragma unroll
        for (int j = 0; j < NTOK; ++j) {
            float dot = 0.f;
#pragma unroll
            for (int d = 0; d < HD; ++d) dot += q[d] * ks[j][d];
            p[j] = dot * invk[j] + rpbrow[j] + mrow[j];
        }
        float mx = -1e30f;
#pragma unroll
        for (int j = 0; j < NTOK; ++j) mx = fmaxf(mx, p[j]);
        float sum = 0.f;
#pragma unroll
        for (int j = 0; j < NTOK; ++j) { p[j] = __expf(p[j] - mx); sum += p[j]; }
        const float rs = 1.f / sum;

        float o[HD];
#pragma unroll
        for (int d = 0; d < HD; ++d) o[d] = 0.f;
#pragma unroll
        for (int j = 0; j < NTOK; ++j) {
            const float pj = p[j];
#pragma unroll
            for (int d = 0; d < HD; ++d) o[d] += pj * vs[j][d];
        }
        __bf16* dst = aout + ((size_t)(b * NTOK + tid)) * CDIM + h * HD;
#pragma unroll
        for (int c = 0; c < HD / 8; ++c) {
            bf16x8 ov;
#pragma unroll
            for (int e = 0; e < 8; ++e) ov[e] = (__bf16)(o[c * 8 + e] * rs);
            *(bf16x8*)(dst + c * 8) = ov;
        }
    }
}

extern "C" void kernel_launch(void* const* d_in, const int* in_sizes, int n_in,
                              void* d_out, int out_size, void* d_ws, size_t ws_size,
                              hipStream_t stream) {
    const float* x      = (const float*)d_in[0];
    const float* mask   = (const float*)d_in[1];
    const float* qkv_w  = (const float*)d_in[2];
    const float* q_bias = (const float*)d_in[3];
    const float* v_bias = (const float*)d_in[4];
    const float* lscale = (const float*)d_in[5];
    const float* cpb_w1 = (const float*)d_in[6];
    const float* cpb_b1 = (const float*)d_in[7];
    const float* cpb_w2 = (const float*)d_in[8];
    const float* proj_w = (const float*)d_in[9];
    const float* proj_b = (const float*)d_in[10];
    float* out = (float*)d_out;

    const size_t QKVELEMS = (size_t)BWIN * NH * NTOK * HD;  // 38,535,168
    __bf16* qkvbuf  = (__bf16*)d_ws;                    // q,k,v
    __bf16* aoutbuf = qkvbuf + 3 * QKVELEMS;            // attn out
    __bf16* qkv_wb  = aoutbuf + QKVELEMS;               // 1152*384 bf16
    __bf16* proj_wb = qkv_wb + 1152 * CDIM;             // 384*384 bf16
    float*  bias_tab = (float*)(proj_wb + CDIM * CDIM); // 169*12
    float*  rpbbuf   = bias_tab + 169 * NH;             // 12*49*49

    hipLaunchKernelGGL(cvt_f32_bf16, dim3((1152 * CDIM / 8 + 255) / 256), dim3(256), 0, stream,
                       qkv_w, qkv_wb, 1152 * CDIM / 8);
    hipLaunchKernelGGL(cvt_f32_bf16, dim3((CDIM * CDIM / 8 + 255) / 256), dim3(256), 0, stream,
                       proj_w, proj_wb, CDIM * CDIM / 8);
    hipLaunchKernelGGL(cpb_mlp_kernel, dim3(8), dim3(256), 0, stream,
                       cpb_w1, cpb_b1, cpb_w2, bias_tab);
    hipLaunchKernelGGL(rpb_kernel, dim3((NH * NTOK * NTOK + 255) / 256), dim3(256), 0, stream,
                       bias_tab, rpbbuf);
    hipLaunchKernelGGL((gemm2<0, 9>), dim3(784 * 9), dim3(256), 0, stream,
                       x, (const __bf16*)nullptr, qkv_wb, q_bias, v_bias, qkvbuf,
                       (float*)nullptr, (const float*)nullptr);
    hipLaunchKernelGGL(attn_kernel, dim3(BWIN * NH), dim3(64), 0, stream,
                       qkvbuf, qkvbuf + QKVELEMS, qkvbuf + 2 * QKVELEMS, mask, rpbbuf, lscale,
                       aoutbuf);
    hipLaunchKernelGGL((gemm2<1, 3>), dim3(784 * 3), dim3(256), 0, stream,
                       (const float*)nullptr, aoutbuf, proj_wb, (const float*)nullptr,
                       (const float*)nullptr, (__bf16*)nullptr, out, proj_b);
}

// Round 3
// 598.885 us; speedup vs baseline: 1.2187x; 1.1289x over previous
//
#include <hip/hip_runtime.h>
#include <hip/hip_bf16.h>
#include <math.h>

#define NTOK 49
#define NH 12
#define HD 32
#define CDIM 384
#define NWIN 64
#define BWIN 2048

typedef __bf16 bf16x8 __attribute__((ext_vector_type(8)));
typedef float f32x4 __attribute__((ext_vector_type(4)));

__device__ __forceinline__ void gload_lds16(const void* g, void* l) {
    __builtin_amdgcn_global_load_lds((const __attribute__((address_space(1))) void*)g,
                                     (__attribute__((address_space(3))) void*)l, 16, 0, 0);
}

// ---------------- fp32 -> bf16 convert (x and weights) ----------------
__global__ void cvt_f32_bf16(const float* __restrict__ src, __bf16* __restrict__ dst, int n8) {
    int i = blockIdx.x * blockDim.x + threadIdx.x;
    if (i >= n8) return;
    f32x4 a = *(const f32x4*)(src + (size_t)i * 8);
    f32x4 b = *(const f32x4*)(src + (size_t)i * 8 + 4);
    bf16x8 o;
#pragma unroll
    for (int e = 0; e < 4; ++e) { o[e] = (__bf16)a[e]; o[e + 4] = (__bf16)b[e]; }
    *(bf16x8*)(dst + (size_t)i * 8) = o;
}

// ---------------- CPB MLP: bias_tab[169][12] ----------------
__global__ void cpb_mlp_kernel(const float* __restrict__ w1, const float* __restrict__ b1,
                               const float* __restrict__ w2, float* __restrict__ bias_tab) {
    int t = blockIdx.x * blockDim.x + threadIdx.x;
    if (t >= 169 * NH) return;
    int r = t / NH, h = t - (t / NH) * NH;
    int i = r / 13, j = r - (r / 13) * 13;
    float a0 = (float)(i - 6) * (8.0f / 6.0f);
    float a1 = (float)(j - 6) * (8.0f / 6.0f);
    float c0 = copysignf(log2f(fabsf(a0) + 1.0f) * (1.0f / 3.0f), a0);
    float c1 = copysignf(log2f(fabsf(a1) + 1.0f) * (1.0f / 3.0f), a1);
    float sum = 0.f;
    for (int k = 0; k < 512; ++k) {
        float hid = c0 * w1[2 * k] + c1 * w1[2 * k + 1] + b1[k];
        hid = fmaxf(hid, 0.f);
        sum += hid * w2[h * 512 + k];
    }
    bias_tab[r * NH + h] = sum;
}

// ---------------- rpb[12][49][49] = 16*sigmoid(bias_tab[rpi]) ----------------
__global__ void rpb_kernel(const float* __restrict__ bias_tab, float* __restrict__ rpb) {
    int idx = blockIdx.x * blockDim.x + threadIdx.x;
    if (idx >= NH * NTOK * NTOK) return;
    int h = idx / (NTOK * NTOK);
    int rem = idx - h * (NTOK * NTOK);
    int i = rem / NTOK, j = rem - (rem / NTOK) * NTOK;
    int chi = i / 7, cwi = i - chi * 7;
    int chj = j / 7, cwj = j - chj * 7;
    int rpi = (chi - chj + 6) * 13 + (cwi - cwj + 6);
    float x = bias_tab[rpi * NH + h];
    rpb[idx] = 16.f / (1.f + __expf(-x));
}

// ---------------- MFMA GEMM v3: 2-phase double-buffered, all-bf16 ----------------
// C = A @ Bt^T (+bias). A bf16 [M][384], Bt bf16 [Ncols][384].
// MODE 0: out -> q/k/v bf16 [b][h][n][d] (+q/v bias). MODE 1: out -> f32 (+proj bias).
// LDS [128][32] bf16 per buffer, 16B slots XOR-swizzled: phys = log ^ ((row>>1)&3),
// achieved via SOURCE-pre-swizzled gload_lds (linear LDS dest, rule #21).
template <int MODE, int NBY>
__global__ __launch_bounds__(256) void gemm3(
    const __bf16* __restrict__ A, const __bf16* __restrict__ Bw,
    const float* __restrict__ qbias, const float* __restrict__ vbias,
    __bf16* __restrict__ qkvout,
    float* __restrict__ fout, const float* __restrict__ fbias)
{
    __shared__ __bf16 As[2][128 * 32];
    __shared__ __bf16 Bs[2][128 * 32];
    const int tid = threadIdx.x;
    const int chunk = (784 * NBY) >> 3;
    const int wg = (blockIdx.x & 7) * chunk + (blockIdx.x >> 3);
    const int gx = wg / NBY, gy = wg - (wg / NBY) * NBY;
    const int lane = tid & 63;
    const int wid = tid >> 6;
    const int wr = (wid >> 1) * 64;
    const int wc = (wid & 1) * 64;
    const int fr = lane & 15;
    const int fq = lane >> 4;

    f32x4 acc[4][4];
#pragma unroll
    for (int m = 0; m < 4; ++m)
#pragma unroll
        for (int n = 0; n < 4; ++n)
            acc[m][n] = (f32x4){0.f, 0.f, 0.f, 0.f};

    // staging geometry: s = r*256+tid -> row = s>>2, 16B chunk cp = s&3
    const int srow0 = tid >> 2, scp0 = tid & 3;
    const int srow1 = (256 + tid) >> 2, scp1 = tid & 3;
    const size_t ar0 = (size_t)(gx * 128 + srow0) * CDIM + (scp0 ^ ((srow0 >> 1) & 3)) * 8;
    const size_t ar1 = (size_t)(gx * 128 + srow1) * CDIM + (scp1 ^ ((srow1 >> 1) & 3)) * 8;
    const size_t br0 = (size_t)(gy * 128 + srow0) * CDIM + (scp0 ^ ((srow0 >> 1) & 3)) * 8;
    const size_t br1 = (size_t)(gy * 128 + srow1) * CDIM + (scp1 ^ ((srow1 >> 1) & 3)) * 8;
    const int ls0 = tid * 16, ls1 = (256 + tid) * 16;  // byte offsets

    // prologue: stage K-tile 0 into buf 0
    gload_lds16(A + ar0, (char*)&As[0][0] + ls0);
    gload_lds16(A + ar1, (char*)&As[0][0] + ls1);
    gload_lds16(Bw + br0, (char*)&Bs[0][0] + ls0);
    gload_lds16(Bw + br1, (char*)&Bs[0][0] + ls1);
    __syncthreads();

#pragma unroll
    for (int t = 0; t < 12; ++t) {
        const int cur = t & 1;
        if (t < 11) {
            const int k = (t + 1) * 32;
            gload_lds16(A + ar0 + k, (char*)&As[cur ^ 1][0] + ls0);
            gload_lds16(A + ar1 + k, (char*)&As[cur ^ 1][0] + ls1);
            gload_lds16(Bw + br0 + k, (char*)&Bs[cur ^ 1][0] + ls0);
            gload_lds16(Bw + br1 + k, (char*)&Bs[cur ^ 1][0] + ls1);
        }
        bf16x8 af[4], bfr[4];
#pragma unroll
        for (int m = 0; m < 4; ++m) {
            const int row = wr + m * 16 + fr;
            af[m] = *(const bf16x8*)&As[cur][row * 32 + (fq ^ ((row >> 1) & 3)) * 8];
        }
#pragma unroll
        for (int n = 0; n < 4; ++n) {
            const int row = wc + n * 16 + fr;
            bfr[n] = *(const bf16x8*)&Bs[cur][row * 32 + (fq ^ ((row >> 1) & 3)) * 8];
        }
#pragma unroll
        for (int m = 0; m < 4; ++m)
#pragma unroll
            for (int n = 0; n < 4; ++n)
                acc[m][n] = __builtin_amdgcn_mfma_f32_16x16x32_bf16(af[m], bfr[n], acc[m][n], 0, 0, 0);
        __syncthreads();  // waits vmcnt(0) too: next buf staged, cur free for overwrite
    }

    if (MODE == 0) {
        const int colbase = gy * 128;
        const int part = colbase / CDIM;
        const int pcolbase = colbase - part * CDIM;
        __bf16* dst = qkvout + (size_t)part * ((size_t)BWIN * NH * NTOK * HD);
#pragma unroll
        for (int m = 0; m < 4; ++m) {
#pragma unroll
            for (int r = 0; r < 4; ++r) {
                const int row = gx * 128 + wr + m * 16 + fq * 4 + r;
                const int b = row / NTOK;
                const int nn = row - b * NTOK;
#pragma unroll
                for (int n = 0; n < 4; ++n) {
                    const int pcol = pcolbase + wc + n * 16 + fr;
                    float val = acc[m][n][r];
                    if (part == 0) val += qbias[pcol];
                    if (part == 2) val += vbias[pcol];
                    const int h = pcol >> 5, d = pcol & 31;
                    dst[(((size_t)b * NH + h) * NTOK + nn) * HD + d] = (__bf16)val;
                }
            }
        }
    } else {
#pragma unroll
        for (int m = 0; m < 4; ++m) {
#pragma unroll
            for (int r = 0; r < 4; ++r) {
                const int row = gx * 128 + wr + m * 16 + fq * 4 + r;
                float* orow = fout + (size_t)row * CDIM + gy * 128 + wc;
#pragma unroll
                for (int n = 0; n < 4; ++n) {
                    const int col = gy * 128 + wc + n * 16 + fr;
                    orow[n * 16 + fr] = acc[m][n][r] + fbias[col];
                }
            }
        }
    }
}

// ---------------- attention: one (b,h) per 64-thread block ----------------
__global__ __launch_bounds__(64) void attn_kernel(
    const __bf16* __restrict__ qb, const __bf16* __restrict__ kb,
    const __bf16* __restrict__ vb, const float* __restrict__ mask,
    const float* __restrict__ rpb, const float* __restrict__ lscale,
    __bf16* __restrict__ aout)
{
    const int bh = blockIdx.x;
    const int b = bh / NH;
    const int h = bh - b * NH;
    const int w = b & (NWIN - 1);
    const int tid = threadIdx.x;

    __shared__ float ks[NTOK][HD];
    __shared__ float vs[NTOK][HD];
    __shared__ float invk[NTOK];

    const __bf16* kg = kb + (size_t)bh * (NTOK * HD);
    const __bf16* vg = vb + (size_t)bh * (NTOK * HD);
    for (int c = tid; c < 2 * NTOK * HD / 8; c += 64) {
        const int mat = (c >= NTOK * HD / 8);
        const int cc = mat ? c - NTOK * HD / 8 : c;
        bf16x8 raw = *(const bf16x8*)((mat ? vg : kg) + cc * 8);
        float* dstf = (mat ? &vs[0][0] : &ks[0][0]) + cc * 8;
#pragma unroll
        for (int e = 0; e < 8; ++e) dstf[e] = (float)raw[e];
    }
    __syncthreads();
    if (tid < NTOK) {
        float s = 0.f;
#pragma unroll
        for (int d = 0; d < HD; ++d) s += ks[tid][d] * ks[tid][d];
        invk[tid] = 1.0f / fmaxf(sqrtf(s), 1e-12f);
    }
    __syncthreads();
    if (tid < NTOK) {
        float q[HD];
        const __bf16* qg = qb + (size_t)bh * (NTOK * HD) + tid * HD;
#pragma unroll
        for (int c = 0; c < HD / 8; ++c) {
            bf16x8 raw = *(const bf16x8*)(qg + c * 8);
#pragma unroll
            for (int e = 0; e < 8; ++e) q[c * 8 + e] = (float)raw[e];
        }
        float s = 0.f;
#pragma unroll
        for (int d = 0; d < HD; ++d) s += q[d] * q[d];
        const float scale = __expf(fminf(lscale[h], 4.6051702f));
        const float pre = scale / fmaxf(sqrtf(s), 1e-12f);
#pragma unroll
        for (int d = 0; d < HD; ++d) q[d] *= pre;

        float p[NTOK];
        const float* rpbrow = rpb + ((size_t)h * NTOK + tid) * NTOK;
        const float* mrow = mask + ((size_t)w * NTOK + tid) * NTOK;
#pragma unroll
        for (int j = 0; j < NTOK; ++j) {
            float dot = 0.f;
#pragma unroll
            for (int d = 0; d < HD; ++d) dot += q[d] * ks[j][d];
            p[j] = dot * invk[j] + rpbrow[j] + mrow[j];
        }
        float mx = -1e30f;
#pragma unroll
        for (int j = 0; j < NTOK; ++j) mx = fmaxf(mx, p[j]);
        float sum = 0.f;
#pragma unroll
        for (int j = 0; j < NTOK; ++j) { p[j] = __expf(p[j] - mx); sum += p[j]; }
        const float rs = 1.f / sum;

        float o[HD];
#pragma unroll
        for (int d = 0; d < HD; ++d) o[d] = 0.f;
#pragma unroll
        for (int j = 0; j < NTOK; ++j) {
            const float pj = p[j];
#pragma unroll
            for (int d = 0; d < HD; ++d) o[d] += pj * vs[j][d];
        }
        __bf16* dst = aout + ((size_t)(b * NTOK + tid)) * CDIM + h * HD;
#pragma unroll
        for (int c = 0; c < HD / 8; ++c) {
            bf16x8 ov;
#pragma unroll
            for (int e = 0; e < 8; ++e) ov[e] = (__bf16)(o[c * 8 + e] * rs);
            *(bf16x8*)(dst + c * 8) = ov;
        }
    }
}

extern "C" void kernel_launch(void* const* d_in, const int* in_sizes, int n_in,
                              void* d_out, int out_size, void* d_ws, size_t ws_size,
                              hipStream_t stream) {
    const float* x      = (const float*)d_in[0];
    const float* mask   = (const float*)d_in[1];
    const float* qkv_w  = (const float*)d_in[2];
    const float* q_bias = (const float*)d_in[3];
    const float* v_bias = (const float*)d_in[4];
    const float* lscale = (const float*)d_in[5];
    const float* cpb_w1 = (const float*)d_in[6];
    const float* cpb_b1 = (const float*)d_in[7];
    const float* cpb_w2 = (const float*)d_in[8];
    const float* proj_w = (const float*)d_in[9];
    const float* proj_b = (const float*)d_in[10];
    float* out = (float*)d_out;

    const size_t QKVELEMS = (size_t)BWIN * NH * NTOK * HD;  // 38,535,168 == 100352*384
    __bf16* qkvbuf  = (__bf16*)d_ws;                    // q,k,v (231 MB)
    __bf16* xbf     = qkvbuf + 3 * QKVELEMS;            // x bf16, later reused as attn out
    __bf16* aoutbuf = xbf;                              // alias: lifetimes disjoint
    __bf16* qkv_wb  = xbf + QKVELEMS;                   // 1152*384 bf16
    __bf16* proj_wb = qkv_wb + 1152 * CDIM;             // 384*384 bf16
    float*  bias_tab = (float*)(proj_wb + CDIM * CDIM); // 169*12
    float*  rpbbuf   = bias_tab + 169 * NH;             // 12*49*49

    hipLaunchKernelGGL(cvt_f32_bf16, dim3((int)((QKVELEMS / 8 + 255) / 256)), dim3(256), 0, stream,
                       x, xbf, (int)(QKVELEMS / 8));
    hipLaunchKernelGGL(cvt_f32_bf16, dim3((1152 * CDIM / 8 + 255) / 256), dim3(256), 0, stream,
                       qkv_w, qkv_wb, 1152 * CDIM / 8);
    hipLaunchKernelGGL(cvt_f32_bf16, dim3((CDIM * CDIM / 8 + 255) / 256), dim3(256), 0, stream,
                       proj_w, proj_wb, CDIM * CDIM / 8);
    hipLaunchKernelGGL(cpb_mlp_kernel, dim3(8), dim3(256), 0, stream,
                       cpb_w1, cpb_b1, cpb_w2, bias_tab);
    hipLaunchKernelGGL(rpb_kernel, dim3((NH * NTOK * NTOK + 255) / 256), dim3(256), 0, stream,
                       bias_tab, rpbbuf);
    hipLaunchKernelGGL((gemm3<0, 9>), dim3(784 * 9), dim3(256), 0, stream,
                       xbf, qkv_wb, q_bias, v_bias, qkvbuf, (float*)nullptr,
                       (const float*)nullptr);
    hipLaunchKernelGGL(attn_kernel, dim3(BWIN * NH), dim3(64), 0, stream,
                       qkvbuf, qkvbuf + QKVELEMS, qkvbuf + 2 * QKVELEMS, mask, rpbbuf, lscale,
                       aoutbuf);
    hipLaunchKernelGGL((gemm3<1, 3>), dim3(784 * 3), dim3(256), 0, stream,
                       aoutbuf, proj_wb, (const float*)nullptr, (const float*)nullptr,
                       (__bf16*)nullptr, out, proj_b);
}

// Round 4
// 467.016 us; speedup vs baseline: 1.5628x; 1.2824x over previous
//
#include <hip/hip_runtime.h>
#include <hip/hip_bf16.h>
#include <math.h>

#define NTOK 49
#define NH 12
#define HD 32
#define CDIM 384
#define NWIN 64
#define BWIN 2048

typedef __bf16 bf16x8 __attribute__((ext_vector_type(8)));
typedef __bf16 bf16x4 __attribute__((ext_vector_type(4)));
typedef float f32x4 __attribute__((ext_vector_type(4)));

__device__ __forceinline__ void gload_lds16(const void* g, void* l) {
    __builtin_amdgcn_global_load_lds((const __attribute__((address_space(1))) void*)g,
                                     (__attribute__((address_space(3))) void*)l, 16, 0, 0);
}

// ---------------- fp32 -> bf16 convert ----------------
__global__ void cvt_f32_bf16(const float* __restrict__ src, __bf16* __restrict__ dst, int n8) {
    int i = blockIdx.x * blockDim.x + threadIdx.x;
    if (i >= n8) return;
    f32x4 a = *(const f32x4*)(src + (size_t)i * 8);
    f32x4 b = *(const f32x4*)(src + (size_t)i * 8 + 4);
    bf16x8 o;
#pragma unroll
    for (int e = 0; e < 4; ++e) { o[e] = (__bf16)a[e]; o[e + 4] = (__bf16)b[e]; }
    *(bf16x8*)(dst + (size_t)i * 8) = o;
}

// ---------------- CPB MLP: bias_tab[169][12] ----------------
__global__ void cpb_mlp_kernel(const float* __restrict__ w1, const float* __restrict__ b1,
                               const float* __restrict__ w2, float* __restrict__ bias_tab) {
    int t = blockIdx.x * blockDim.x + threadIdx.x;
    if (t >= 169 * NH) return;
    int r = t / NH, h = t - (t / NH) * NH;
    int i = r / 13, j = r - (r / 13) * 13;
    float a0 = (float)(i - 6) * (8.0f / 6.0f);
    float a1 = (float)(j - 6) * (8.0f / 6.0f);
    float c0 = copysignf(log2f(fabsf(a0) + 1.0f) * (1.0f / 3.0f), a0);
    float c1 = copysignf(log2f(fabsf(a1) + 1.0f) * (1.0f / 3.0f), a1);
    float sum = 0.f;
    for (int k = 0; k < 512; ++k) {
        float hid = c0 * w1[2 * k] + c1 * w1[2 * k + 1] + b1[k];
        hid = fmaxf(hid, 0.f);
        sum += hid * w2[h * 512 + k];
    }
    bias_tab[r * NH + h] = sum;
}

// ---------------- rpbT[h][k][q] = 16*sigmoid(bias_tab[rpi(q,k)][h]) ----------------
__global__ void rpbT_kernel(const float* __restrict__ bias_tab, float* __restrict__ rpbT) {
    int idx = blockIdx.x * blockDim.x + threadIdx.x;
    if (idx >= NH * NTOK * NTOK) return;
    int h = idx / (NTOK * NTOK);
    int rem = idx - h * (NTOK * NTOK);
    int kj = rem / NTOK, qi = rem - (rem / NTOK) * NTOK;  // write [h][kj][qi]
    int chi = qi / 7, cwi = qi - chi * 7;                  // rpi(i=qi, j=kj)
    int chj = kj / 7, cwj = kj - chj * 7;
    int rpi = (chi - chj + 6) * 13 + (cwi - cwj + 6);
    float x = bias_tab[rpi * NH + h];
    rpbT[idx] = 16.f / (1.f + __expf(-x));
}

// ---------------- maskT[w][k][q] = mask[w][q][k] ----------------
__global__ void maskT_kernel(const float* __restrict__ mask, float* __restrict__ maskT) {
    int idx = blockIdx.x * blockDim.x + threadIdx.x;
    if (idx >= NWIN * NTOK * NTOK) return;
    int w = idx / (NTOK * NTOK);
    int rem = idx - w * (NTOK * NTOK);
    int kj = rem / NTOK, qi = rem - (rem / NTOK) * NTOK;
    maskT[idx] = mask[(w * NTOK + qi) * NTOK + kj];
}

// ---------------- MFMA GEMM: 2-phase double-buffered, all-bf16 ----------------
template <int MODE, int NBY>
__global__ __launch_bounds__(256) void gemm3(
    const __bf16* __restrict__ A, const __bf16* __restrict__ Bw,
    const float* __restrict__ qbias, const float* __restrict__ vbias,
    __bf16* __restrict__ qkvout,
    float* __restrict__ fout, const float* __restrict__ fbias)
{
    __shared__ __bf16 As[2][128 * 32];
    __shared__ __bf16 Bs[2][128 * 32];
    const int tid = threadIdx.x;
    const int chunk = (784 * NBY) >> 3;
    const int wg = (blockIdx.x & 7) * chunk + (blockIdx.x >> 3);
    const int gx = wg / NBY, gy = wg - (wg / NBY) * NBY;
    const int lane = tid & 63;
    const int wid = tid >> 6;
    const int wr = (wid >> 1) * 64;
    const int wc = (wid & 1) * 64;
    const int fr = lane & 15;
    const int fq = lane >> 4;

    f32x4 acc[4][4];
#pragma unroll
    for (int m = 0; m < 4; ++m)
#pragma unroll
        for (int n = 0; n < 4; ++n)
            acc[m][n] = (f32x4){0.f, 0.f, 0.f, 0.f};

    const int srow0 = tid >> 2, scp0 = tid & 3;
    const int srow1 = (256 + tid) >> 2, scp1 = tid & 3;
    const size_t ar0 = (size_t)(gx * 128 + srow0) * CDIM + (scp0 ^ ((srow0 >> 1) & 3)) * 8;
    const size_t ar1 = (size_t)(gx * 128 + srow1) * CDIM + (scp1 ^ ((srow1 >> 1) & 3)) * 8;
    const size_t br0 = (size_t)(gy * 128 + srow0) * CDIM + (scp0 ^ ((srow0 >> 1) & 3)) * 8;
    const size_t br1 = (size_t)(gy * 128 + srow1) * CDIM + (scp1 ^ ((srow1 >> 1) & 3)) * 8;
    const int ls0 = tid * 16, ls1 = (256 + tid) * 16;

    gload_lds16(A + ar0, (char*)&As[0][0] + ls0);
    gload_lds16(A + ar1, (char*)&As[0][0] + ls1);
    gload_lds16(Bw + br0, (char*)&Bs[0][0] + ls0);
    gload_lds16(Bw + br1, (char*)&Bs[0][0] + ls1);
    __syncthreads();

#pragma unroll
    for (int t = 0; t < 12; ++t) {
        const int cur = t & 1;
        if (t < 11) {
            const int k = (t + 1) * 32;
            gload_lds16(A + ar0 + k, (char*)&As[cur ^ 1][0] + ls0);
            gload_lds16(A + ar1 + k, (char*)&As[cur ^ 1][0] + ls1);
            gload_lds16(Bw + br0 + k, (char*)&Bs[cur ^ 1][0] + ls0);
            gload_lds16(Bw + br1 + k, (char*)&Bs[cur ^ 1][0] + ls1);
        }
        bf16x8 af[4], bfr[4];
#pragma unroll
        for (int m = 0; m < 4; ++m) {
            const int row = wr + m * 16 + fr;
            af[m] = *(const bf16x8*)&As[cur][row * 32 + (fq ^ ((row >> 1) & 3)) * 8];
        }
#pragma unroll
        for (int n = 0; n < 4; ++n) {
            const int row = wc + n * 16 + fr;
            bfr[n] = *(const bf16x8*)&Bs[cur][row * 32 + (fq ^ ((row >> 1) & 3)) * 8];
        }
#pragma unroll
        for (int m = 0; m < 4; ++m)
#pragma unroll
            for (int n = 0; n < 4; ++n)
                acc[m][n] = __builtin_amdgcn_mfma_f32_16x16x32_bf16(af[m], bfr[n], acc[m][n], 0, 0, 0);
        __syncthreads();
    }

    if (MODE == 0) {
        const int colbase = gy * 128;
        const int part = colbase / CDIM;
        const int pcolbase = colbase - part * CDIM;
        __bf16* dst = qkvout + (size_t)part * ((size_t)BWIN * NH * NTOK * HD);
#pragma unroll
        for (int m = 0; m < 4; ++m) {
#pragma unroll
            for (int r = 0; r < 4; ++r) {
                const int row = gx * 128 + wr + m * 16 + fq * 4 + r;
                const int b = row / NTOK;
                const int nn = row - b * NTOK;
#pragma unroll
                for (int n = 0; n < 4; ++n) {
                    const int pcol = pcolbase + wc + n * 16 + fr;
                    float val = acc[m][n][r];
                    if (part == 0) val += qbias[pcol];
                    if (part == 2) val += vbias[pcol];
                    const int h = pcol >> 5, d = pcol & 31;
                    dst[(((size_t)b * NH + h) * NTOK + nn) * HD + d] = (__bf16)val;
                }
            }
        }
    } else {
#pragma unroll
        for (int m = 0; m < 4; ++m) {
#pragma unroll
            for (int r = 0; r < 4; ++r) {
                const int row = gx * 128 + wr + m * 16 + fq * 4 + r;
                float* orow = fout + (size_t)row * CDIM + gy * 128 + wc;
#pragma unroll
                for (int n = 0; n < 4; ++n) {
                    const int col = gy * 128 + wc + n * 16 + fr;
                    orow[n * 16 + fr] = acc[m][n][r] + fbias[col];
                }
            }
        }
    }
}

// ---------------- attention v2: MFMA, one (b,h) per wave, 4 waves/block ----------------
// Per-wave LDS region (15872 B): K[64][40]bf16 @0, Q[64][40] @5120, V[64][40] @10240,
// invq f32[64] @15360, invk f32[64] @15616. P[64][72]bf16 overlays K+Q @0.
#define WREG 15872
__global__ __launch_bounds__(256) void attn2(
    const __bf16* __restrict__ qb, const __bf16* __restrict__ kb,
    const __bf16* __restrict__ vb, const float* __restrict__ maskT,
    const float* __restrict__ rpbT, const float* __restrict__ lscale,
    __bf16* __restrict__ aout)
{
    __shared__ char smem[4 * WREG];
    const int tid = threadIdx.x;
    const int wid = tid >> 6, lane = tid & 63;
    const int bh = blockIdx.x * 4 + wid;
    const int b = bh / NH, h = bh - b * NH;
    const int w = b & (NWIN - 1);
    const int c = lane & 15, g = lane >> 4;

    char* base = smem + wid * WREG;
    __bf16* Kl = (__bf16*)base;
    __bf16* Ql = (__bf16*)(base + 5120);
    __bf16* Vl = (__bf16*)(base + 10240);
    float* invq = (float*)(base + 15360);
    float* invk = (float*)(base + 15616);
    __bf16* Pl = (__bf16*)base;  // overlays K+Q after QK^T

    const float sc = __expf(fminf(lscale[h], 4.6051702f));

    // ---- stage raw bf16 rows + norms (lane = row) ----
    {
        const int row = lane;
        const size_t rb = (size_t)bh * (NTOK * HD) + (size_t)row * HD;
        bf16x8 z;
#pragma unroll
        for (int e = 0; e < 8; ++e) z[e] = (__bf16)0.f;
        // Q
        {
            bf16x8 t[4];
            float ss = 0.f;
            if (row < NTOK) {
#pragma unroll
                for (int ch = 0; ch < 4; ++ch) {
                    t[ch] = *(const bf16x8*)(qb + rb + ch * 8);
#pragma unroll
                    for (int e = 0; e < 8; ++e) { float f = (float)t[ch][e]; ss += f * f; }
                }
            } else {
#pragma unroll
                for (int ch = 0; ch < 4; ++ch) t[ch] = z;
            }
#pragma unroll
            for (int ch = 0; ch < 4; ++ch) *(bf16x8*)&Ql[row * 40 + ch * 8] = t[ch];
            invq[row] = sc / fmaxf(sqrtf(ss), 1e-12f);
        }
        // K
        {
            bf16x8 t[4];
            float ss = 0.f;
            if (row < NTOK) {
#pragma unroll
                for (int ch = 0; ch < 4; ++ch) {
                    t[ch] = *(const bf16x8*)(kb + rb + ch * 8);
#pragma unroll
                    for (int e = 0; e < 8; ++e) { float f = (float)t[ch][e]; ss += f * f; }
                }
            } else {
#pragma unroll
                for (int ch = 0; ch < 4; ++ch) t[ch] = z;
            }
#pragma unroll
            for (int ch = 0; ch < 4; ++ch) *(bf16x8*)&Kl[row * 40 + ch * 8] = t[ch];
            invk[row] = 1.f / fmaxf(sqrtf(ss), 1e-12f);
        }
        // V (raw copy)
        {
            bf16x8 t[4];
            if (row < NTOK) {
#pragma unroll
                for (int ch = 0; ch < 4; ++ch) t[ch] = *(const bf16x8*)(vb + rb + ch * 8);
            } else {
#pragma unroll
                for (int ch = 0; ch < 4; ++ch) t[ch] = z;
            }
#pragma unroll
            for (int ch = 0; ch < 4; ++ch) *(bf16x8*)&Vl[row * 40 + ch * 8] = t[ch];
        }
    }

    // ---- S^T = K · Q^T  (swapped: rows=k, cols=q) ----
    bf16x8 kfr[4], qfr[4];
#pragma unroll
    for (int mt = 0; mt < 4; ++mt) kfr[mt] = *(const bf16x8*)&Kl[(mt * 16 + c) * 40 + g * 8];
#pragma unroll
    for (int nt = 0; nt < 4; ++nt) qfr[nt] = *(const bf16x8*)&Ql[(nt * 16 + c) * 40 + g * 8];
    f32x4 S[4][4];
#pragma unroll
    for (int mt = 0; mt < 4; ++mt)
#pragma unroll
        for (int nt = 0; nt < 4; ++nt) {
            S[mt][nt] = (f32x4){0.f, 0.f, 0.f, 0.f};
            S[mt][nt] = __builtin_amdgcn_mfma_f32_16x16x32_bf16(kfr[mt], qfr[nt], S[mt][nt], 0, 0, 0);
        }

    // ---- scale by invk[k]*invq[q], add rpbT+maskT, pad k>=49 -> -1e30 ----
    const float* rp = rpbT + h * (NTOK * NTOK);
    const float* mk = maskT + w * (NTOK * NTOK);
    float ivq[4];
#pragma unroll
    for (int nt = 0; nt < 4; ++nt) ivq[nt] = invq[nt * 16 + c];
#pragma unroll
    for (int mt = 0; mt < 4; ++mt) {
#pragma unroll
        for (int r = 0; r < 4; ++r) {
            const int k = mt * 16 + g * 4 + r;
            const float ivk = invk[k];
#pragma unroll
            for (int nt = 0; nt < 4; ++nt) {
                const int q = nt * 16 + c;
                float v = S[mt][nt][r] * ivk * ivq[nt];
                if (k < NTOK) {
                    if (q < NTOK) v += rp[k * NTOK + q] + mk[k * NTOK + q];
                } else {
                    v = -1e30f;
                }
                S[mt][nt][r] = v;
            }
        }
    }

    // ---- softmax over k (in-lane 16 + shfl_xor 16,32), fold 1/sum into P ----
    float rs[4];
#pragma unroll
    for (int nt = 0; nt < 4; ++nt) {
        float m = -1e30f;
#pragma unroll
        for (int mt = 0; mt < 4; ++mt)
#pragma unroll
            for (int r = 0; r < 4; ++r) m = fmaxf(m, S[mt][nt][r]);
        m = fmaxf(m, __shfl_xor(m, 16));
        m = fmaxf(m, __shfl_xor(m, 32));
        float s = 0.f;
#pragma unroll
        for (int mt = 0; mt < 4; ++mt)
#pragma unroll
            for (int r = 0; r < 4; ++r) {
                float e = __expf(S[mt][nt][r] - m);
                S[mt][nt][r] = e;
                s += e;
            }
        s += __shfl_xor(s, 16);
        s += __shfl_xor(s, 32);
        rs[nt] = 1.f / s;
    }

    // ---- P -> bf16 -> LDS [q][k] (stride 72 bf16 = 144 B) ----
#pragma unroll
    for (int mt = 0; mt < 4; ++mt)
#pragma unroll
        for (int nt = 0; nt < 4; ++nt) {
            bf16x4 pk;
#pragma unroll
            for (int r = 0; r < 4; ++r) pk[r] = (__bf16)(S[mt][nt][r] * rs[nt]);
            *(bf16x4*)((char*)Pl + (nt * 16 + c) * 144 + (mt * 16 + g * 4) * 2) = pk;
        }

    // ---- O = P · V ----
    bf16x8 vfr[2][2];
#pragma unroll
    for (int kt = 0; kt < 2; ++kt)
#pragma unroll
        for (int dt = 0; dt < 2; ++dt) {
            bf16x8 t;
#pragma unroll
            for (int e = 0; e < 8; ++e) t[e] = Vl[(kt * 32 + g * 8 + e) * 40 + dt * 16 + c];
            vfr[kt][dt] = t;
        }
    f32x4 O[4][2];
#pragma unroll
    for (int mt = 0; mt < 4; ++mt)
#pragma unroll
        for (int dt = 0; dt < 2; ++dt) O[mt][dt] = (f32x4){0.f, 0.f, 0.f, 0.f};
#pragma unroll
    for (int mt = 0; mt < 4; ++mt)
#pragma unroll
        for (int kt = 0; kt < 2; ++kt) {
            bf16x8 pfr = *(const bf16x8*)((char*)Pl + (mt * 16 + c) * 144 + kt * 64 + g * 16);
#pragma unroll
            for (int dt = 0; dt < 2; ++dt)
                O[mt][dt] = __builtin_amdgcn_mfma_f32_16x16x32_bf16(pfr, vfr[kt][dt], O[mt][dt], 0, 0, 0);
        }

    // ---- store O rows q<49 ----
#pragma unroll
    for (int mt = 0; mt < 4; ++mt)
#pragma unroll
        for (int r = 0; r < 4; ++r) {
            const int q = mt * 16 + g * 4 + r;
            if (q < NTOK) {
                const size_t off = ((size_t)b * NTOK + q) * CDIM + h * HD;
                aout[off + c] = (__bf16)O[mt][0][r];
                aout[off + 16 + c] = (__bf16)O[mt][1][r];
            }
        }
}

extern "C" void kernel_launch(void* const* d_in, const int* in_sizes, int n_in,
                              void* d_out, int out_size, void* d_ws, size_t ws_size,
                              hipStream_t stream) {
    const float* x      = (const float*)d_in[0];
    const float* mask   = (const float*)d_in[1];
    const float* qkv_w  = (const float*)d_in[2];
    const float* q_bias = (const float*)d_in[3];
    const float* v_bias = (const float*)d_in[4];
    const float* lscale = (const float*)d_in[5];
    const float* cpb_w1 = (const float*)d_in[6];
    const float* cpb_b1 = (const float*)d_in[7];
    const float* cpb_w2 = (const float*)d_in[8];
    const float* proj_w = (const float*)d_in[9];
    const float* proj_b = (const float*)d_in[10];
    float* out = (float*)d_out;

    const size_t QKVELEMS = (size_t)BWIN * NH * NTOK * HD;  // 100352*384
    __bf16* qkvbuf  = (__bf16*)d_ws;
    __bf16* xbf     = qkvbuf + 3 * QKVELEMS;   // later reused as attn out
    __bf16* aoutbuf = xbf;
    __bf16* qkv_wb  = xbf + QKVELEMS;
    __bf16* proj_wb = qkv_wb + 1152 * CDIM;
    float*  bias_tab = (float*)(proj_wb + CDIM * CDIM);
    float*  rpbT   = bias_tab + 169 * NH;
    float*  maskT  = rpbT + NH * NTOK * NTOK;

    hipLaunchKernelGGL(cvt_f32_bf16, dim3((int)((QKVELEMS / 8 + 255) / 256)), dim3(256), 0, stream,
                       x, xbf, (int)(QKVELEMS / 8));
    hipLaunchKernelGGL(cvt_f32_bf16, dim3((1152 * CDIM / 8 + 255) / 256), dim3(256), 0, stream,
                       qkv_w, qkv_wb, 1152 * CDIM / 8);
    hipLaunchKernelGGL(cvt_f32_bf16, dim3((CDIM * CDIM / 8 + 255) / 256), dim3(256), 0, stream,
                       proj_w, proj_wb, CDIM * CDIM / 8);
    hipLaunchKernelGGL(cpb_mlp_kernel, dim3(8), dim3(256), 0, stream,
                       cpb_w1, cpb_b1, cpb_w2, bias_tab);
    hipLaunchKernelGGL(rpbT_kernel, dim3((NH * NTOK * NTOK + 255) / 256), dim3(256), 0, stream,
                       bias_tab, rpbT);
    hipLaunchKernelGGL(maskT_kernel, dim3((NWIN * NTOK * NTOK + 255) / 256), dim3(256), 0, stream,
                       mask, maskT);
    hipLaunchKernelGGL((gemm3<0, 9>), dim3(784 * 9), dim3(256), 0, stream,
                       xbf, qkv_wb, q_bias, v_bias, qkvbuf, (float*)nullptr,
                       (const float*)nullptr);
    hipLaunchKernelGGL(attn2, dim3(BWIN * NH / 4), dim3(256), 0, stream,
                       qkvbuf, qkvbuf + QKVELEMS, qkvbuf + 2 * QKVELEMS, maskT, rpbT, lscale,
                       aoutbuf);
    hipLaunchKernelGGL((gemm3<1, 3>), dim3(784 * 3), dim3(256), 0, stream,
                       aoutbuf, proj_wb, (const float*)nullptr, (const float*)nullptr,
                       (__bf16*)nullptr, out, proj_b);
}

// Round 5
// 462.426 us; speedup vs baseline: 1.5783x; 1.0099x over previous
//
#include <hip/hip_runtime.h>
#include <hip/hip_bf16.h>
#include <math.h>

#define NTOK 49
#define NH 12
#define HD 32
#define CDIM 384
#define NWIN 64
#define BWIN 2048

typedef __bf16 bf16x8 __attribute__((ext_vector_type(8)));
typedef __bf16 bf16x4 __attribute__((ext_vector_type(4)));
typedef float f32x4 __attribute__((ext_vector_type(4)));

__device__ __forceinline__ void gload_lds16(const void* g, void* l) {
    __builtin_amdgcn_global_load_lds((const __attribute__((address_space(1))) void*)g,
                                     (__attribute__((address_space(3))) void*)l, 16, 0, 0);
}

// ---------------- fp32 -> bf16 convert ----------------
__global__ void cvt_f32_bf16(const float* __restrict__ src, __bf16* __restrict__ dst, int n8) {
    int i = blockIdx.x * blockDim.x + threadIdx.x;
    if (i >= n8) return;
    f32x4 a = *(const f32x4*)(src + (size_t)i * 8);
    f32x4 b = *(const f32x4*)(src + (size_t)i * 8 + 4);
    bf16x8 o;
#pragma unroll
    for (int e = 0; e < 4; ++e) { o[e] = (__bf16)a[e]; o[e + 4] = (__bf16)b[e]; }
    *(bf16x8*)(dst + (size_t)i * 8) = o;
}

// ---------------- CPB MLP: bias_tab[169][12] ----------------
__global__ void cpb_mlp_kernel(const float* __restrict__ w1, const float* __restrict__ b1,
                               const float* __restrict__ w2, float* __restrict__ bias_tab) {
    int t = blockIdx.x * blockDim.x + threadIdx.x;
    if (t >= 169 * NH) return;
    int r = t / NH, h = t - (t / NH) * NH;
    int i = r / 13, j = r - (r / 13) * 13;
    float a0 = (float)(i - 6) * (8.0f / 6.0f);
    float a1 = (float)(j - 6) * (8.0f / 6.0f);
    float c0 = copysignf(log2f(fabsf(a0) + 1.0f) * (1.0f / 3.0f), a0);
    float c1 = copysignf(log2f(fabsf(a1) + 1.0f) * (1.0f / 3.0f), a1);
    float sum = 0.f;
    for (int k = 0; k < 512; ++k) {
        float hid = c0 * w1[2 * k] + c1 * w1[2 * k + 1] + b1[k];
        hid = fmaxf(hid, 0.f);
        sum += hid * w2[h * 512 + k];
    }
    bias_tab[r * NH + h] = sum;
}

// ---------------- rpbT[h][k][q] = 16*sigmoid(bias_tab[rpi(q,k)][h]) ----------------
__global__ void rpbT_kernel(const float* __restrict__ bias_tab, float* __restrict__ rpbT) {
    int idx = blockIdx.x * blockDim.x + threadIdx.x;
    if (idx >= NH * NTOK * NTOK) return;
    int h = idx / (NTOK * NTOK);
    int rem = idx - h * (NTOK * NTOK);
    int kj = rem / NTOK, qi = rem - (rem / NTOK) * NTOK;
    int chi = qi / 7, cwi = qi - chi * 7;
    int chj = kj / 7, cwj = kj - chj * 7;
    int rpi = (chi - chj + 6) * 13 + (cwi - cwj + 6);
    float x = bias_tab[rpi * NH + h];
    rpbT[idx] = 16.f / (1.f + __expf(-x));
}

// ---------------- maskT[w][k][q] = mask[w][q][k] ----------------
__global__ void maskT_kernel(const float* __restrict__ mask, float* __restrict__ maskT) {
    int idx = blockIdx.x * blockDim.x + threadIdx.x;
    if (idx >= NWIN * NTOK * NTOK) return;
    int w = idx / (NTOK * NTOK);
    int rem = idx - w * (NTOK * NTOK);
    int kj = rem / NTOK, qi = rem - (rem / NTOK) * NTOK;
    maskT[idx] = mask[(w * NTOK + qi) * NTOK + kj];
}

// ---------------- MFMA GEMM v4: 3-buffer 2-deep prefetch, counted vmcnt ----------------
// C = A @ Bt^T (+bias). A bf16 [M][384], Bt bf16 [Ncols][384].
// LDS [128][32] bf16 per buffer, 16B slots XOR-swizzled: phys = log ^ ((row>>1)&3),
// via SOURCE-pre-swizzled gload_lds (linear dest, rule #21).
// Pipeline: prologue stages tiles 0,1; iter t: vmcnt(4) [tile t landed, t+1 in
// flight] -> s_barrier [cross-wave: everyone done reading buf[(t+2)%3] at iter
// t-1] -> issue tile t+2 -> ds_read+MFMA buf[t%3]. Never drains vmcnt to 0 mid-loop (T4).
template <int MODE, int NBY>
__global__ __launch_bounds__(256) void gemm4(
    const __bf16* __restrict__ A, const __bf16* __restrict__ Bw,
    const float* __restrict__ qbias, const float* __restrict__ vbias,
    __bf16* __restrict__ qkvout,
    float* __restrict__ fout, const float* __restrict__ fbias)
{
    __shared__ __bf16 As[3][128 * 32];
    __shared__ __bf16 Bs[3][128 * 32];
    const int tid = threadIdx.x;
    const int chunk = (784 * NBY) >> 3;
    const int wg = (blockIdx.x & 7) * chunk + (blockIdx.x >> 3);
    const int gx = wg / NBY, gy = wg - (wg / NBY) * NBY;
    const int lane = tid & 63;
    const int wid = tid >> 6;
    const int wr = (wid >> 1) * 64;
    const int wc = (wid & 1) * 64;
    const int fr = lane & 15;
    const int fq = lane >> 4;

    f32x4 acc[4][4];
#pragma unroll
    for (int m = 0; m < 4; ++m)
#pragma unroll
        for (int n = 0; n < 4; ++n)
            acc[m][n] = (f32x4){0.f, 0.f, 0.f, 0.f};

    const int srow0 = tid >> 2, scp0 = tid & 3;
    const int srow1 = (256 + tid) >> 2, scp1 = tid & 3;
    const size_t ar0 = (size_t)(gx * 128 + srow0) * CDIM + (scp0 ^ ((srow0 >> 1) & 3)) * 8;
    const size_t ar1 = (size_t)(gx * 128 + srow1) * CDIM + (scp1 ^ ((srow1 >> 1) & 3)) * 8;
    const size_t br0 = (size_t)(gy * 128 + srow0) * CDIM + (scp0 ^ ((srow0 >> 1) & 3)) * 8;
    const size_t br1 = (size_t)(gy * 128 + srow1) * CDIM + (scp1 ^ ((srow1 >> 1) & 3)) * 8;
    const int ls0 = tid * 16, ls1 = (256 + tid) * 16;

#define STAGE4(ti, buf) do {                                            \
        const int kk_ = (ti) * 32;                                      \
        gload_lds16(A + ar0 + kk_, (char*)&As[buf][0] + ls0);           \
        gload_lds16(A + ar1 + kk_, (char*)&As[buf][0] + ls1);           \
        gload_lds16(Bw + br0 + kk_, (char*)&Bs[buf][0] + ls0);          \
        gload_lds16(Bw + br1 + kk_, (char*)&Bs[buf][0] + ls1);          \
    } while (0)

    STAGE4(0, 0);
    STAGE4(1, 1);

#pragma unroll
    for (int t = 0; t < 12; ++t) {
        if (t < 11) asm volatile("s_waitcnt vmcnt(4)" ::: "memory");
        else        asm volatile("s_waitcnt vmcnt(0)" ::: "memory");
        __builtin_amdgcn_s_barrier();
        if (t + 2 < 12) STAGE4(t + 2, (t + 2) % 3);
        const int cur = t % 3;
        bf16x8 af[4], bfr[4];
#pragma unroll
        for (int m = 0; m < 4; ++m) {
            const int row = wr + m * 16 + fr;
            af[m] = *(const bf16x8*)&As[cur][row * 32 + (fq ^ ((row >> 1) & 3)) * 8];
        }
#pragma unroll
        for (int n = 0; n < 4; ++n) {
            const int row = wc + n * 16 + fr;
            bfr[n] = *(const bf16x8*)&Bs[cur][row * 32 + (fq ^ ((row >> 1) & 3)) * 8];
        }
#pragma unroll
        for (int m = 0; m < 4; ++m)
#pragma unroll
            for (int n = 0; n < 4; ++n)
                acc[m][n] = __builtin_amdgcn_mfma_f32_16x16x32_bf16(af[m], bfr[n], acc[m][n], 0, 0, 0);
    }
#undef STAGE4

    if (MODE == 0) {
        const int colbase = gy * 128;
        const int part = colbase / CDIM;
        const int pcolbase = colbase - part * CDIM;
        __bf16* dst = qkvout + (size_t)part * ((size_t)BWIN * NH * NTOK * HD);
#pragma unroll
        for (int m = 0; m < 4; ++m) {
#pragma unroll
            for (int r = 0; r < 4; ++r) {
                const int row = gx * 128 + wr + m * 16 + fq * 4 + r;
                const int b = row / NTOK;
                const int nn = row - b * NTOK;
#pragma unroll
                for (int n = 0; n < 4; ++n) {
                    const int pcol = pcolbase + wc + n * 16 + fr;
                    float val = acc[m][n][r];
                    if (part == 0) val += qbias[pcol];
                    if (part == 2) val += vbias[pcol];
                    const int h = pcol >> 5, d = pcol & 31;
                    dst[(((size_t)b * NH + h) * NTOK + nn) * HD + d] = (__bf16)val;
                }
            }
        }
    } else {
#pragma unroll
        for (int m = 0; m < 4; ++m) {
#pragma unroll
            for (int r = 0; r < 4; ++r) {
                const int row = gx * 128 + wr + m * 16 + fq * 4 + r;
                float* orow = fout + (size_t)row * CDIM + gy * 128 + wc;
#pragma unroll
                for (int n = 0; n < 4; ++n) {
                    const int col = gy * 128 + wc + n * 16 + fr;
                    orow[n * 16 + fr] = acc[m][n][r] + fbias[col];
                }
            }
        }
    }
}

// ---------------- attention v2: MFMA, one (b,h) per wave, 4 waves/block ----------------
#define WREG 15872
__global__ __launch_bounds__(256) void attn2(
    const __bf16* __restrict__ qb, const __bf16* __restrict__ kb,
    const __bf16* __restrict__ vb, const float* __restrict__ maskT,
    const float* __restrict__ rpbT, const float* __restrict__ lscale,
    __bf16* __restrict__ aout)
{
    __shared__ char smem[4 * WREG];
    const int tid = threadIdx.x;
    const int wid = tid >> 6, lane = tid & 63;
    const int bh = blockIdx.x * 4 + wid;
    const int b = bh / NH, h = bh - b * NH;
    const int w = b & (NWIN - 1);
    const int c = lane & 15, g = lane >> 4;

    char* base = smem + wid * WREG;
    __bf16* Kl = (__bf16*)base;
    __bf16* Ql = (__bf16*)(base + 5120);
    __bf16* Vl = (__bf16*)(base + 10240);
    float* invq = (float*)(base + 15360);
    float* invk = (float*)(base + 15616);
    __bf16* Pl = (__bf16*)base;

    const float sc = __expf(fminf(lscale[h], 4.6051702f));

    {
        const int row = lane;
        const size_t rb = (size_t)bh * (NTOK * HD) + (size_t)row * HD;
        bf16x8 z;
#pragma unroll
        for (int e = 0; e < 8; ++e) z[e] = (__bf16)0.f;
        {
            bf16x8 t[4];
            float ss = 0.f;
            if (row < NTOK) {
#pragma unroll
                for (int ch = 0; ch < 4; ++ch) {
                    t[ch] = *(const bf16x8*)(qb + rb + ch * 8);
#pragma unroll
                    for (int e = 0; e < 8; ++e) { float f = (float)t[ch][e]; ss += f * f; }
                }
            } else {
#pragma unroll
                for (int ch = 0; ch < 4; ++ch) t[ch] = z;
            }
#pragma unroll
            for (int ch = 0; ch < 4; ++ch) *(bf16x8*)&Ql[row * 40 + ch * 8] = t[ch];
            invq[row] = sc / fmaxf(sqrtf(ss), 1e-12f);
        }
        {
            bf16x8 t[4];
            float ss = 0.f;
            if (row < NTOK) {
#pragma unroll
                for (int ch = 0; ch < 4; ++ch) {
                    t[ch] = *(const bf16x8*)(kb + rb + ch * 8);
#pragma unroll
                    for (int e = 0; e < 8; ++e) { float f = (float)t[ch][e]; ss += f * f; }
                }
            } else {
#pragma unroll
                for (int ch = 0; ch < 4; ++ch) t[ch] = z;
            }
#pragma unroll
            for (int ch = 0; ch < 4; ++ch) *(bf16x8*)&Kl[row * 40 + ch * 8] = t[ch];
            invk[row] = 1.f / fmaxf(sqrtf(ss), 1e-12f);
        }
        {
            bf16x8 t[4];
            if (row < NTOK) {
#pragma unroll
                for (int ch = 0; ch < 4; ++ch) t[ch] = *(const bf16x8*)(vb + rb + ch * 8);
            } else {
#pragma unroll
                for (int ch = 0; ch < 4; ++ch) t[ch] = z;
            }
#pragma unroll
            for (int ch = 0; ch < 4; ++ch) *(bf16x8*)&Vl[row * 40 + ch * 8] = t[ch];
        }
    }

    bf16x8 kfr[4], qfr[4];
#pragma unroll
    for (int mt = 0; mt < 4; ++mt) kfr[mt] = *(const bf16x8*)&Kl[(mt * 16 + c) * 40 + g * 8];
#pragma unroll
    for (int nt = 0; nt < 4; ++nt) qfr[nt] = *(const bf16x8*)&Ql[(nt * 16 + c) * 40 + g * 8];
    f32x4 S[4][4];
#pragma unroll
    for (int mt = 0; mt < 4; ++mt)
#pragma unroll
        for (int nt = 0; nt < 4; ++nt) {
            S[mt][nt] = (f32x4){0.f, 0.f, 0.f, 0.f};
            S[mt][nt] = __builtin_amdgcn_mfma_f32_16x16x32_bf16(kfr[mt], qfr[nt], S[mt][nt], 0, 0, 0);
        }

    const float* rp = rpbT + h * (NTOK * NTOK);
    const float* mk = maskT + w * (NTOK * NTOK);
    float ivq[4];
#pragma unroll
    for (int nt = 0; nt < 4; ++nt) ivq[nt] = invq[nt * 16 + c];
#pragma unroll
    for (int mt = 0; mt < 4; ++mt) {
#pragma unroll
        for (int r = 0; r < 4; ++r) {
            const int k = mt * 16 + g * 4 + r;
            const float ivk = invk[k];
#pragma unroll
            for (int nt = 0; nt < 4; ++nt) {
                const int q = nt * 16 + c;
                float v = S[mt][nt][r] * ivk * ivq[nt];
                if (k < NTOK) {
                    if (q < NTOK) v += rp[k * NTOK + q] + mk[k * NTOK + q];
                } else {
                    v = -1e30f;
                }
                S[mt][nt][r] = v;
            }
        }
    }

    float rs[4];
#pragma unroll
    for (int nt = 0; nt < 4; ++nt) {
        float m = -1e30f;
#pragma unroll
        for (int mt = 0; mt < 4; ++mt)
#pragma unroll
            for (int r = 0; r < 4; ++r) m = fmaxf(m, S[mt][nt][r]);
        m = fmaxf(m, __shfl_xor(m, 16));
        m = fmaxf(m, __shfl_xor(m, 32));
        float s = 0.f;
#pragma unroll
        for (int mt = 0; mt < 4; ++mt)
#pragma unroll
            for (int r = 0; r < 4; ++r) {
                float e = __expf(S[mt][nt][r] - m);
                S[mt][nt][r] = e;
                s += e;
            }
        s += __shfl_xor(s, 16);
        s += __shfl_xor(s, 32);
        rs[nt] = 1.f / s;
    }

#pragma unroll
    for (int mt = 0; mt < 4; ++mt)
#pragma unroll
        for (int nt = 0; nt < 4; ++nt) {
            bf16x4 pk;
#pragma unroll
            for (int r = 0; r < 4; ++r) pk[r] = (__bf16)(S[mt][nt][r] * rs[nt]);
            *(bf16x4*)((char*)Pl + (nt * 16 + c) * 144 + (mt * 16 + g * 4) * 2) = pk;
        }

    bf16x8 vfr[2][2];
#pragma unroll
    for (int kt = 0; kt < 2; ++kt)
#pragma unroll
        for (int dt = 0; dt < 2; ++dt) {
            bf16x8 t;
#pragma unroll
            for (int e = 0; e < 8; ++e) t[e] = Vl[(kt * 32 + g * 8 + e) * 40 + dt * 16 + c];
            vfr[kt][dt] = t;
        }
    f32x4 O[4][2];
#pragma unroll
    for (int mt = 0; mt < 4; ++mt)
#pragma unroll
        for (int dt = 0; dt < 2; ++dt) O[mt][dt] = (f32x4){0.f, 0.f, 0.f, 0.f};
#pragma unroll
    for (int mt = 0; mt < 4; ++mt)
#pragma unroll
        for (int kt = 0; kt < 2; ++kt) {
            bf16x8 pfr = *(const bf16x8*)((char*)Pl + (mt * 16 + c) * 144 + kt * 64 + g * 16);
#pragma unroll
            for (int dt = 0; dt < 2; ++dt)
                O[mt][dt] = __builtin_amdgcn_mfma_f32_16x16x32_bf16(pfr, vfr[kt][dt], O[mt][dt], 0, 0, 0);
        }

#pragma unroll
    for (int mt = 0; mt < 4; ++mt)
#pragma unroll
        for (int r = 0; r < 4; ++r) {
            const int q = mt * 16 + g * 4 + r;
            if (q < NTOK) {
                const size_t off = ((size_t)b * NTOK + q) * CDIM + h * HD;
                aout[off + c] = (__bf16)O[mt][0][r];
                aout[off + 16 + c] = (__bf16)O[mt][1][r];
            }
        }
}

extern "C" void kernel_launch(void* const* d_in, const int* in_sizes, int n_in,
                              void* d_out, int out_size, void* d_ws, size_t ws_size,
                              hipStream_t stream) {
    const float* x      = (const float*)d_in[0];
    const float* mask   = (const float*)d_in[1];
    const float* qkv_w  = (const float*)d_in[2];
    const float* q_bias = (const float*)d_in[3];
    const float* v_bias = (const float*)d_in[4];
    const float* lscale = (const float*)d_in[5];
    const float* cpb_w1 = (const float*)d_in[6];
    const float* cpb_b1 = (const float*)d_in[7];
    const float* cpb_w2 = (const float*)d_in[8];
    const float* proj_w = (const float*)d_in[9];
    const float* proj_b = (const float*)d_in[10];
    float* out = (float*)d_out;

    const size_t QKVELEMS = (size_t)BWIN * NH * NTOK * HD;  // 100352*384
    __bf16* qkvbuf  = (__bf16*)d_ws;
    __bf16* xbf     = qkvbuf + 3 * QKVELEMS;   // later reused as attn out
    __bf16* aoutbuf = xbf;
    __bf16* qkv_wb  = xbf + QKVELEMS;
    __bf16* proj_wb = qkv_wb + 1152 * CDIM;
    float*  bias_tab = (float*)(proj_wb + CDIM * CDIM);
    float*  rpbT   = bias_tab + 169 * NH;
    float*  maskT  = rpbT + NH * NTOK * NTOK;

    hipLaunchKernelGGL(cvt_f32_bf16, dim3((int)((QKVELEMS / 8 + 255) / 256)), dim3(256), 0, stream,
                       x, xbf, (int)(QKVELEMS / 8));
    hipLaunchKernelGGL(cvt_f32_bf16, dim3((1152 * CDIM / 8 + 255) / 256), dim3(256), 0, stream,
                       qkv_w, qkv_wb, 1152 * CDIM / 8);
    hipLaunchKernelGGL(cvt_f32_bf16, dim3((CDIM * CDIM / 8 + 255) / 256), dim3(256), 0, stream,
                       proj_w, proj_wb, CDIM * CDIM / 8);
    hipLaunchKernelGGL(cpb_mlp_kernel, dim3(8), dim3(256), 0, stream,
                       cpb_w1, cpb_b1, cpb_w2, bias_tab);
    hipLaunchKernelGGL(rpbT_kernel, dim3((NH * NTOK * NTOK + 255) / 256), dim3(256), 0, stream,
                       bias_tab, rpbT);
    hipLaunchKernelGGL(maskT_kernel, dim3((NWIN * NTOK * NTOK + 255) / 256), dim3(256), 0, stream,
                       mask, maskT);
    hipLaunchKernelGGL((gemm4<0, 9>), dim3(784 * 9), dim3(256), 0, stream,
                       xbf, qkv_wb, q_bias, v_bias, qkvbuf, (float*)nullptr,
                       (const float*)nullptr);
    hipLaunchKernelGGL(attn2, dim3(BWIN * NH / 4), dim3(256), 0, stream,
                       qkvbuf, qkvbuf + QKVELEMS, qkvbuf + 2 * QKVELEMS, maskT, rpbT, lscale,
                       aoutbuf);
    hipLaunchKernelGGL((gemm4<1, 3>), dim3(784 * 3), dim3(256), 0, stream,
                       aoutbuf, proj_wb, (const float*)nullptr, (const float*)nullptr,
                       (__bf16*)nullptr, out, proj_b);
}